// Round 14
// baseline (71.119 us; speedup 1.0000x reference)
//
#include <hip/hip_runtime.h>

#define BDIM 128
#define TDIM 512
#define DDIM 64
#define HDIM 256
#define BH   (BDIM * HDIM)            // 32768
#define HH_OFF (4 * BH)               // hh: B x 1024 after the 4 partial planes

typedef short s16x8 __attribute__((ext_vector_type(8)));
typedef float f32x4 __attribute__((ext_vector_type(4)));

#if __has_builtin(__builtin_amdgcn_exp2f)
#define EXP2(x) __builtin_amdgcn_exp2f(x)
#else
#define EXP2(x) exp2f(x)
#endif
#define L2E 1.44269504f

__device__ __forceinline__ float rcpf(float x) { return __builtin_amdgcn_rcpf(x); }

__device__ __forceinline__ short f2bf(float f) {
  __bf16 b = (__bf16)f;
  return __builtin_bit_cast(short, b);
}

__device__ __forceinline__ s16x8 pack_bf8(float4 lo, float4 hi) {
  s16x8 v;
  v[0] = f2bf(lo.x); v[1] = f2bf(lo.y); v[2] = f2bf(lo.z); v[3] = f2bf(lo.w);
  v[4] = f2bf(hi.x); v[5] = f2bf(hi.y); v[6] = f2bf(hi.z); v[7] = f2bf(hi.w);
  return v;
}

__device__ __forceinline__ s16x8 pack_bf8s(float4 lo, float4 hi, float s) {
  s16x8 v;
  v[0] = f2bf(lo.x*s); v[1] = f2bf(lo.y*s); v[2] = f2bf(lo.z*s); v[3] = f2bf(lo.w*s);
  v[4] = f2bf(hi.x*s); v[5] = f2bf(hi.y*s); v[6] = f2bf(hi.z*s); v[7] = f2bf(hi.w*s);
  return v;
}

// hh = h0 @ Whh^T + bih + bhh via MFMA (R13, verified: total -12us).
__global__ __launch_bounds__(256) void hh_mfma_kernel(
    const float* __restrict__ h0, const float* __restrict__ Whh,
    const float* __restrict__ bih, const float* __restrict__ bhh,
    float* __restrict__ hh)
{
  const int bt   = blockIdx.x;          // 0..7  (16 b's)
  const int nt   = blockIdx.y;          // 0..15 (64 cols)
  const int tid  = threadIdx.x;
  const int wave = tid >> 6;            // 0..3
  const int lane = tid & 63;
  const int col  = lane & 15;
  const int kg   = lane >> 4;           // 0..3
  const int b0   = bt * 16;
  const int colw = nt * 64 + wave * 16 + col;

  const float bias = bih[colw] + bhh[colw];

  const float* arow = h0  + (size_t)(b0 + col) * HDIM + kg * 8;
  const float* brow = Whh + (size_t)colw * HDIM + kg * 8;

  f32x4 acc = {0.f, 0.f, 0.f, 0.f};
  #pragma unroll
  for (int s = 0; s < 8; ++s) {
    float4 a0 = *(const float4*)(arow + s * 32);
    float4 a1 = *(const float4*)(arow + s * 32 + 4);
    float4 q0 = *(const float4*)(brow + s * 32);
    float4 q1 = *(const float4*)(brow + s * 32 + 4);
    acc = __builtin_amdgcn_mfma_f32_16x16x32_bf16(
        pack_bf8(a0, a1), pack_bf8(q0, q1), acc, 0, 0, 0);
  }

  #pragma unroll
  for (int r = 0; r < 4; ++r) {
    const int m = kg * 4 + r;           // b-local row
    hh[(size_t)(b0 + m) * 1024 + colw] = acc[r] + bias;
  }
}

// Grid: (128, 8), 512 threads = 8 waves, zero in-loop barriers/DS ops.
// SWAPPED-OPERAND variant: mfma(A=Wih, B=x) -> C col = t, row = h-local.
// Loads are byte-identical to R8/R12; only the operand order changes. Now
// w0/w1 are PER-LANE SCALARS (t = t0w+tb+col), preloaded into 16 regs from a
// block-staged LDS table — the 64 in-loop ds_bpermute ops (8/step, inside the
// MFMA->cell-math dependency chain, each ~30-40cy + lgkmcnt serialization)
// are gone. cprev/hhv become per-lane 4-vectors (hhv = the f32x4 C-init).
__global__ __launch_bounds__(512, 4) void fused_lstm(
    const float* __restrict__ x, const float* __restrict__ c0,
    const float* __restrict__ Wih, const int* __restrict__ longp,
    float* __restrict__ sbuf)
{
  const int b    = blockIdx.x;
  const int hcq  = blockIdx.y;          // 0..7
  const int tid  = threadIdx.x;
  const int wave = tid >> 6;            // 0..7
  const int lane = tid & 63;
  const int col  = lane & 15;
  const int kg   = lane >> 4;           // 0..3
  const int hp   = wave & 1;
  const int tq   = wave >> 1;           // 0..3
  const int hbase = hcq * 32 + hp * 16;

  __shared__ float2 ws01[TDIM];         // 4KB: {x[t][0] (t=0 zeroed), x[t][1]}
  __shared__ float red[8 * 64];

  const float* hh = sbuf + HH_OFF;
  const float* xb = x + (size_t)b * (TDIM * DDIM);
  const float inv_long = 1.0f / (float)(*longp);

  {
    const float2 v = *(const float2*)(xb + (size_t)tid * DDIM);
    ws01[tid] = (tid == 0) ? make_float2(0.f, 0.f) : v;   // t=0 mask baked in
  }
  __syncthreads();

  const int t0w = tq * 128;

  // per-step w0/w1 scalars for this lane: t = t0w + i*16 + col (16 regs)
  float w0r[8], w1r[8];
  #pragma unroll
  for (int i = 0; i < 8; ++i) {
    float2 v = ws01[t0w + i * 16 + col];
    w0r[i] = v.x; w1r[i] = v.y;
  }

  const float SC[4] = {L2E, L2E, 2.f * L2E, L2E};
  // hhv[g] = f32x4 over r (h = hbase + kg*4 + r) — exactly the C-init vector
  f32x4 hhv4[4];
  float cprev[4];
  #pragma unroll
  for (int r = 0; r < 4; ++r) {
    const int h = hbase + kg * 4 + r;
    cprev[r] = c0[b * HDIM + h];
    #pragma unroll
    for (int g = 0; g < 4; ++g)
      hhv4[g][r] = hh[(size_t)b * 1024 + g * HDIM + h] * SC[g];
  }

  // Wih fragments — SAME lane->(h=hbase+col, k=kg*8+j) map as before, now fed
  // to the A slot (m = h). Pre-scaled by SC[g].
  s16x8 wf[4][2];
  #pragma unroll
  for (int g = 0; g < 4; ++g) {
    const float4* wrow = (const float4*)(Wih + (size_t)(g * HDIM + hbase + col) * DDIM);
    #pragma unroll
    for (int ks = 0; ks < 2; ++ks)
      wf[g][ks] = pack_bf8s(wrow[kg * 2 + ks * 8], wrow[kg * 2 + ks * 8 + 1], SC[g]);
  }

  // x fragments — SAME addresses as before, now the B slot (n = t).
  const float* arow = xb + (size_t)(t0w + col) * DDIM + kg * 8;

  float4 nxt0 = *(const float4*)(arow + 0);
  float4 nxt1 = *(const float4*)(arow + 4);
  float4 nxt2 = *(const float4*)(arow + 32);
  float4 nxt3 = *(const float4*)(arow + 36);
  s16x8 a0 = pack_bf8(nxt0, nxt1);
  s16x8 a1 = pack_bf8(nxt2, nxt3);

  float s0h[4] = {0,0,0,0}, s1h[4] = {0,0,0,0};
  float s0c[4] = {0,0,0,0}, s1c[4] = {0,0,0,0};

  #pragma unroll
  for (int i = 0; i < 8; ++i) {
    const bool has_next = (i + 1) < 8;
    if (has_next) {
      const float* p = arow + (size_t)((i + 1) * 16) * DDIM;
      nxt0 = *(const float4*)(p + 0);
      nxt1 = *(const float4*)(p + 4);
      nxt2 = *(const float4*)(p + 32);
      nxt3 = *(const float4*)(p + 36);
    }

    f32x4 acc[4];
    #pragma unroll
    for (int g = 0; g < 4; ++g) {
      f32x4 zc = hhv4[g];                          // bias+hh folded into C
      zc = __builtin_amdgcn_mfma_f32_16x16x32_bf16(wf[g][0], a0, zc, 0, 0, 0);
      zc = __builtin_amdgcn_mfma_f32_16x16x32_bf16(wf[g][1], a1, zc, 0, 0, 0);
      acc[g] = zc;
    }

    const float wx = w0r[i], wy = w1r[i];          // lane-local, zero DS ops
    #pragma unroll
    for (int r = 0; r < 4; ++r) {                  // r indexes h = hbase+kg*4+r
      float ig = rcpf(1.f + EXP2(-acc[0][r]));
      float fg = rcpf(1.f + EXP2(-acc[1][r]));
      float gg = fmaf(-2.f, rcpf(EXP2(acc[2][r]) + 1.f), 1.f);
      float og = rcpf(1.f + EXP2(-acc[3][r]));
      float cc = fmaf(fg, cprev[r], ig * gg);
      float th = fmaf(-2.f, rcpf(EXP2(cc * (2.f * L2E)) + 1.f), 1.f);
      float hv = og * th;
      s0h[r] = fmaf(hv, wx, s0h[r]); s1h[r] = fmaf(hv, wy, s1h[r]);
      s0c[r] = fmaf(cc, wx, s0c[r]); s1c[r] = fmaf(cc, wy, s1c[r]);
    }

    if (has_next) {
      a0 = pack_bf8(nxt0, nxt1);
      a1 = pack_bf8(nxt2, nxt3);
    }
  }

  // reduce over the 16 t-columns within each kg group (once, post-loop)
  #pragma unroll
  for (int r = 0; r < 4; ++r) {
    #pragma unroll
    for (int off = 1; off < 16; off <<= 1) {
      s0h[r] += __shfl_xor(s0h[r], off, 64);
      s1h[r] += __shfl_xor(s1h[r], off, 64);
      s0c[r] += __shfl_xor(s0c[r], off, 64);
      s1c[r] += __shfl_xor(s1c[r], off, 64);
    }
  }

  if (col == 0) {
    #pragma unroll
    for (int r = 0; r < 4; ++r) {
      const int hl = kg * 4 + r;
      red[wave * 64 +  0 + hl] = s0h[r] * inv_long;   // /long folded here
      red[wave * 64 + 16 + hl] = s1h[r];
      red[wave * 64 + 32 + hl] = s0c[r] * inv_long;
      red[wave * 64 + 48 + hl] = s1c[r];
    }
  }
  __syncthreads();

  // combine the 4 t-quarters per h-slice (waves {hp, 2+hp, 4+hp, 6+hp})
  if (tid < 128) {
    const int hp2 = tid >> 6;
    const int q   = (tid >> 4) & 3;
    const int cc2 = tid & 15;
    const int o   = q * 16 + cc2;
    float s = red[(0 + hp2) * 64 + o] + red[(2 + hp2) * 64 + o] +
              red[(4 + hp2) * 64 + o] + red[(6 + hp2) * 64 + o];
    const int h2 = hcq * 32 + hp2 * 16 + cc2;
    sbuf[(size_t)q * BH + b * HDIM + h2] = s;
  }
}

// Grid: 128 blocks (b), 256 threads. W0/W1 sums (once per b) + GEMV epilogue.
__global__ __launch_bounds__(256) void out_kernel(
    const float* __restrict__ x, const float* __restrict__ f1w,
    const float* __restrict__ f1b, const float* __restrict__ f2w,
    const float* __restrict__ f2b, const int* __restrict__ longp,
    const float* __restrict__ sbuf, float* __restrict__ out)
{
  const int b = blockIdx.x, tid = threadIdx.x;
  __shared__ float s0h[256], s1h[256], s0c[256], s1c[256];
  __shared__ float wsum[8];
  const float* xb = x + (size_t)b * (TDIM * DDIM);

  s0h[tid] = sbuf[(size_t)0 * BH + b * HDIM + tid];
  s1h[tid] = sbuf[(size_t)1 * BH + b * HDIM + tid];
  s0c[tid] = sbuf[(size_t)2 * BH + b * HDIM + tid];
  s1c[tid] = sbuf[(size_t)3 * BH + b * HDIM + tid];

  float w0p = 0.f, w1p = 0.f;
  for (int t = tid; t < TDIM; t += 256) {
    float2 v = *(const float2*)(xb + (size_t)t * DDIM);
    w0p += v.x; w1p += v.y;
  }
  #pragma unroll
  for (int off = 1; off < 64; off <<= 1) {
    w0p += __shfl_xor(w0p, off, 64);
    w1p += __shfl_xor(w1p, off, 64);
  }
  if ((tid & 63) == 0) { wsum[tid >> 6] = w0p; wsum[4 + (tid >> 6)] = w1p; }
  __syncthreads();

  const float inv_long = 1.0f / (float)(*longp);
  const float W0 = (wsum[0] + wsum[1] + wsum[2] + wsum[3]) * inv_long; // all t
  const float W1 = (wsum[4] + wsum[5] + wsum[6] + wsum[7]);

  float rh, rc;
  if (tid < 128) {                       // "first": f1_w with w0-weighted sums
    const float4* wr = (const float4*)(f1w + (size_t)tid * HDIM);
    float ah = 0.f, ac = 0.f;
    #pragma unroll 8
    for (int k = 0; k < HDIM / 4; ++k) {
      float4 w = wr[k];
      ah += w.x * s0h[4*k] + w.y * s0h[4*k+1] + w.z * s0h[4*k+2] + w.w * s0h[4*k+3];
      ac += w.x * s0c[4*k] + w.y * s0c[4*k+1] + w.z * s0c[4*k+2] + w.w * s0c[4*k+3];
    }
    const float bb = f1b[tid];
    rh = ah + bb * W0;
    rc = ac + bb * W0;
  } else {                               // "second": f2_w with w1-weighted sums
    const int k0 = tid - 128;
    const float4* wr = (const float4*)(f2w + (size_t)k0 * HDIM);
    float ah = 0.f, ac = 0.f;
    #pragma unroll 8
    for (int k = 0; k < HDIM / 4; ++k) {
      float4 w = wr[k];
      ah += w.x * s1h[4*k] + w.y * s1h[4*k+1] + w.z * s1h[4*k+2] + w.w * s1h[4*k+3];
      ac += w.x * s1c[4*k] + w.y * s1c[4*k+1] + w.z * s1c[4*k+2] + w.w * s1c[4*k+3];
    }
    const float bb = f2b[k0];
    rh = ah + bb * W1;
    rc = ac + bb * W1;
  }
  out[b * HDIM + tid] = rh;                      // agg(h_all) -> (1,B,256)
  out[BDIM * HDIM + b * HDIM + tid] = rc;        // agg(c_all)
}

extern "C" void kernel_launch(void* const* d_in, const int* in_sizes, int n_in,
                              void* d_out, int out_size, void* d_ws, size_t ws_size,
                              hipStream_t stream) {
  const float* x   = (const float*)d_in[0];
  const float* h0  = (const float*)d_in[1];
  const float* c0  = (const float*)d_in[2];
  const float* Wih = (const float*)d_in[3];
  const float* Whh = (const float*)d_in[4];
  const float* bih = (const float*)d_in[5];
  const float* bhh = (const float*)d_in[6];
  const float* f1w = (const float*)d_in[7];
  const float* f1b = (const float*)d_in[8];
  const float* f2w = (const float*)d_in[9];
  const float* f2b = (const float*)d_in[10];
  const int*  longp = (const int*)d_in[11];
  float* out  = (float*)d_out;
  float* sbuf = (float*)d_ws;   // planes 512KB + hh 512KB

  dim3 gh(8, 16);
  hh_mfma_kernel<<<gh, 256, 0, stream>>>(h0, Whh, bih, bhh, sbuf + HH_OFF);
  dim3 g1(BDIM, 8);
  fused_lstm<<<g1, 512, 0, stream>>>(x, c0, Wih, longp, sbuf);
  out_kernel<<<BDIM, 256, 0, stream>>>(x, f1w, f1b, f2w, f2b, longp, sbuf, out);
}